// Round 16
// baseline (8694.377 us; speedup 1.0000x reference)
//
#include <hip/hip_runtime.h>

// InputFeedRNNDecoder on MI355X.  T=100 B=64 S=602 H=1024 E=512 V=10000.
// === ABLATION ROUND: r15 kernel + P4 stream executed TWICE (second pass
// kept alive via asm, no output writes) to measure P4's marginal cost. ===
// Persistent kernel: 256 blocks x 256 threads (1 block/CU, 4 waves), 100
// steps, 5 fence-free global barriers/step (store-slot + relay release).
// Coherence: write-once rings (sc0sc1 stores / cached loads); c-state in
// block-exclusive tiles; out/attns write-through.
// GEMM: direct cached global A-fragment loads, 4-way k-split, LDS reduce.
// Attention: fixed-shift exact softmax; 4-deep row pipeline in P4.

#define DI __device__ __forceinline__

typedef __attribute__((ext_vector_type(4))) short s4v;
typedef __attribute__((ext_vector_type(8))) short s8v;
typedef __attribute__((ext_vector_type(4))) float f4v;

DI float b2f(short u) {
  unsigned int x = ((unsigned int)(unsigned short)u) << 16;
  float f; __builtin_memcpy(&f, &x, 4); return f;
}
DI short f2b(float f) {  // round-to-nearest-even
  unsigned int x; __builtin_memcpy(&x, &f, 4);
  return (short)((x + 0x7fffu + ((x >> 16) & 1u)) >> 16);
}
DI s8v cat8(s4v lo, s4v hi) {
  s8v r; r[0]=lo[0];r[1]=lo[1];r[2]=lo[2];r[3]=lo[3];
  r[4]=hi[0];r[5]=hi[1];r[6]=hi[2];r[7]=hi[3]; return r;
}
DI f4v mfma16(s8v a, s8v b, f4v c) {
  return __builtin_amdgcn_mfma_f32_16x16x32_bf16(a, b, c, 0, 0, 0);
}
DI float sigm(float x) { return 1.f / (1.f + __expf(-x)); }

// ---- coherent access helpers (system scope, cache-bypassing) --------------
DI unsigned long long ld64c(const void* p) {
  return __hip_atomic_load((const unsigned long long*)p, __ATOMIC_RELAXED,
                           __HIP_MEMORY_SCOPE_SYSTEM);
}
DI void st64c(void* p, unsigned long long v) {
  __hip_atomic_store((unsigned long long*)p, v, __ATOMIC_RELAXED,
                     __HIP_MEMORY_SCOPE_SYSTEM);
}
DI float ldfc(const float* p) {
  return __hip_atomic_load(p, __ATOMIC_RELAXED, __HIP_MEMORY_SCOPE_SYSTEM);
}
DI void stfc(float* p, float v) {
  __hip_atomic_store(p, v, __ATOMIC_RELAXED, __HIP_MEMORY_SCOPE_SYSTEM);
}
DI int ld32c(const int* p) {
  return __hip_atomic_load(p, __ATOMIC_RELAXED, __HIP_MEMORY_SCOPE_SYSTEM);
}
DI void st32c(int* p, int v) {
  __hip_atomic_store(p, v, __ATOMIC_RELAXED, __HIP_MEMORY_SCOPE_SYSTEM);
}
DI void st16c(short* p, short v) {    // 16-bit write-through store
  asm volatile("global_store_short %0, %1, off sc0 sc1"
               :: "v"(p), "v"((unsigned int)(unsigned short)v) : "memory");
}
union U64S { unsigned long long u; short s[4]; };
union U64F { unsigned long long u; float f[2]; };

// ---------------- packing kernels (run once per call) ----------------------

__global__ void cvt_bf16(const float* __restrict__ src, short* __restrict__ dst, long n8) {
  long i = (long)blockIdx.x * blockDim.x + threadIdx.x;
  long stride = (long)gridDim.x * blockDim.x;
  for (; i < n8; i += stride) {
    const float* s = src + i * 8;
    s8v o;
    #pragma unroll
    for (int j = 0; j < 8; ++j) o[j] = f2b(s[j]);
    *(s8v*)(dst + i * 8) = o;
  }
}

// dst[(kt*N + n)*32 + k32] = W[n][kt*32+k32]  with W = [WA | WB] along k.
__global__ void pack_w(const float* __restrict__ WA, int Ka,
                       const float* __restrict__ WB, int Kb,
                       short* __restrict__ dst, int N, long total) {
  long i = (long)blockIdx.x * blockDim.x + threadIdx.x;
  long stride = (long)gridDim.x * blockDim.x;
  for (; i < total; i += stride) {
    int c = (int)(i & 3);
    long r = i >> 2;
    int n = (int)(r % N);
    int kt = (int)(r / N);
    int k = kt * 32 + c * 8;
    const float* s = (k < Ka) ? (WA + (size_t)n * Ka + k)
                              : (WB + (size_t)n * Kb + (k - Ka));
    s8v o;
    #pragma unroll
    for (int j = 0; j < 8; ++j) o[j] = f2b(s[j]);
    *(s8v*)(dst + r * 32 + c * 8) = o;
  }
}

__global__ __launch_bounds__(64) void emb_gather(const int* __restrict__ tgt,
                                                 const float* __restrict__ emb,
                                                 short* __restrict__ dst) {
  int tb = blockIdx.x;                // 0..6399 = t*64+b
  int idx = tgt[tb];
  const float* s = emb + (size_t)idx * 512 + threadIdx.x * 8;
  s8v o;
  #pragma unroll
  for (int j = 0; j < 8; ++j) o[j] = f2b(s[j]);
  *(s8v*)(dst + (size_t)tb * 512 + threadIdx.x * 8) = o;
}

// c-state tile layout: c[bid*256 + lr*16 + lc], bid = (row>>4)*64 + (col>>4),
// lr = row&15, lc = col&15  -> every 1KB tile is exclusively one block's.
__global__ void init_state(const float* __restrict__ h0, const float* __restrict__ c0,
                           short* __restrict__ h0r, short* __restrict__ h1r,
                           float* __restrict__ c0buf, float* __restrict__ c1buf,
                           short* __restrict__ feedr) {
  int i = blockIdx.x * 256 + threadIdx.x;
  if (i < 65536) {
    h0r[i] = f2b(h0[i]);          // ring slot 0
    h1r[i] = f2b(h0[65536 + i]);
    int row = i >> 10, col = i & 1023;
    size_t coff = (size_t)((row >> 4) * 64 + (col >> 4)) * 256
                + (row & 15) * 16 + (col & 15);
    c0buf[coff] = c0[i];
    c1buf[coff] = c0[65536 + i];
    feedr[i] = 0;                 // bf16 zero, slot 0
  }
}

// ---------------- GEMM core: direct cached global A loads ------------------

template <int NG>
DI void kloop(const short* __restrict__ A, int ld, int nkt,
              const short* __restrict__ Wp, size_t wkt,
              f4v* acc, int rA, int g) {
  if (nkt <= 0) return;
  const short* ap = A + (size_t)rA * ld + 4 * g;
  s4v alo = *(const s4v*)ap, ahi = *(const s4v*)(ap + 16);
  s4v blo[NG], bhi[NG];
  #pragma unroll
  for (int t = 0; t < NG; ++t) {
    blo[t] = *(const s4v*)(Wp + (size_t)t * 32768);
    bhi[t] = *(const s4v*)(Wp + (size_t)t * 32768 + 16);
  }
  for (int kt = 0; kt < nkt - 1; ++kt) {
    const short* apn = ap + (kt + 1) * 32;
    const short* bpn = Wp + (size_t)(kt + 1) * wkt;
    s4v nalo = *(const s4v*)apn, nahi = *(const s4v*)(apn + 16);
    s4v nblo[NG], nbhi[NG];
    #pragma unroll
    for (int t = 0; t < NG; ++t) {
      nblo[t] = *(const s4v*)(bpn + (size_t)t * 32768);
      nbhi[t] = *(const s4v*)(bpn + (size_t)t * 32768 + 16);
    }
    s8v a = cat8(alo, ahi);
    #pragma unroll
    for (int t = 0; t < NG; ++t) acc[t] = mfma16(a, cat8(blo[t], bhi[t]), acc[t]);
    alo = nalo; ahi = nahi;
    #pragma unroll
    for (int t = 0; t < NG; ++t) { blo[t] = nblo[t]; bhi[t] = nbhi[t]; }
  }
  s8v a = cat8(alo, ahi);
  #pragma unroll
  for (int t = 0; t < NG; ++t) acc[t] = mfma16(a, cat8(blo[t], bhi[t]), acc[t]);
}

// Up to 3 K-segments; this wave covers global k-tiles [k0,k1).
template <int NG>
DI void seg_gemm(const short* __restrict__ A0, int ld0, int n0,
                 const short* __restrict__ A1, int ld1, int n1,
                 const short* __restrict__ A2, int ld2, int n2,
                 const short* __restrict__ wbase, size_t wkt,
                 int k0, int k1, f4v* acc, int rA, int g) {
  int s = 0;
  {
    int a = k0 > s ? k0 : s, b = k1 < (s + n0) ? k1 : (s + n0);
    if (a < b) kloop<NG>(A0 + (size_t)(a - s) * 32, ld0, b - a,
                         wbase + (size_t)a * wkt, wkt, acc, rA, g);
    s += n0;
  }
  {
    int a = k0 > s ? k0 : s, b = k1 < (s + n1) ? k1 : (s + n1);
    if (a < b) kloop<NG>(A1 + (size_t)(a - s) * 32, ld1, b - a,
                         wbase + (size_t)a * wkt, wkt, acc, rA, g);
    s += n1;
  }
  if (n2 > 0) {
    int a = k0 > s ? k0 : s, b = k1 < (s + n2) ? k1 : (s + n2);
    if (a < b) kloop<NG>(A2 + (size_t)(a - s) * 32, ld2, b - a,
                         wbase + (size_t)a * wkt, wkt, acc, rA, g);
  }
}

// Sum the 4 waves' partial accumulators via LDS. Wave 0 holds the total.
template <int NG>
DI void wave_reduce(f4v* acc, float* smem, int w, int l) {
  #pragma unroll
  for (int t4 = 0; t4 < NG; ++t4)
    *(f4v*)&smem[(w * 64 + l) * 20 + t4 * 4] = acc[t4];
  __syncthreads();
  if (w == 0) {
    #pragma unroll
    for (int t4 = 0; t4 < NG; ++t4) {
      f4v s0 = *(f4v*)&smem[l * 20 + t4 * 4];
      #pragma unroll
      for (int ww = 1; ww < 4; ++ww) {
        f4v v = *(f4v*)&smem[(ww * 64 + l) * 20 + t4 * 4];
        #pragma unroll
        for (int j = 0; j < 4; ++j) s0[j] += v[j];
      }
      acc[t4] = s0;
    }
  }
}

// ---- store-slot barrier with hierarchical 16-way relay release ------------
// bar ints: slot for block i at i*16 (i=1..255); relay[j] at 4160 + j*16
// (j=0..15, 16 pollers each); per-b attn counters at 6144 + b*16. Monotonic.

DI void gbar(int* bar, int bid, int want) {
  __syncthreads();
  int tid = threadIdx.x;
  if (bid == 0) {
    for (;;) {
      int ok = 1;
      if (tid > 0) ok = (ld32c(bar + tid * 16) >= want);
      if (__syncthreads_and(ok)) break;
      __builtin_amdgcn_s_sleep(1);
    }
    if (tid < 16) st32c(bar + 4160 + tid * 16, want);   // 16-way relay fanout
  } else {
    if (tid == 0) {
      st32c(bar + bid * 16, want);
      const int* relay = bar + 4160 + (bid >> 4) * 16;
      while (ld32c(relay) < want) __builtin_amdgcn_s_sleep(8);
    }
  }
  __syncthreads();
}

// ---------------- the persistent decoder kernel ----------------------------

__global__ __launch_bounds__(256, 1) void decoder_k(
    const short* __restrict__ W0p, const short* __restrict__ W1p,
    const short* __restrict__ Wop, const short* __restrict__ Wap,
    const short* __restrict__ emba,
    const float* __restrict__ bi0, const float* __restrict__ bh0,
    const float* __restrict__ bi1, const float* __restrict__ bh1,
    short* h0r, short* h1r, short* feedr, short* ctxr, short* qb,
    float* c0b, float* c1b, float* alg, float* part, float* csum,
    const short* __restrict__ Mb, const float* __restrict__ memf,
    float* out, int useMb, int* bar) {
  __shared__ float smem[5248];
  const int bid = blockIdx.x, tid = threadIdx.x;
  const int w = tid >> 6, l = tid & 63, r15 = l & 15, g = l >> 4;
  // XCD-colocating remap: the 4 blocks sharing a weight slice (same cs) are
  // bid = cs + {0,64,128,192} == cs (mod 8) -> same XCD under round-robin.
  const int cs = bid & 63, rt = bid >> 6;
  int barno = 0;
  f4v z = {0.f, 0.f, 0.f, 0.f};

  for (int t = 0; t < 100; ++t) {
    const size_t scur = (size_t)t * 65536, snxt = (size_t)(t + 1) * 65536;

    // ---- P1: LSTM0 gates (N=4096, K=2560: emb512|feed1024|h0 1024) ----
    {
      f4v acc[4] = {z, z, z, z};
      const short* wbase = W0p + (size_t)(cs * 16 + r15) * 32 + 4 * g;
      seg_gemm<4>(emba + (size_t)t * 64 * 512, 512, 16,
                  feedr + scur, 1024, 32, h0r + scur, 1024, 32,
                  wbase, (size_t)4096 * 32, w * 20, w * 20 + 20,
                  acc, rt * 16 + r15, g);
      wave_reduce<4>(acc, smem, w, l);
      if (w == 0) {
        int h = cs * 16 + r15;
        float bs0 = bi0[h] + bh0[h];
        float bs1 = bi0[1024 + h] + bh0[1024 + h];
        float bs2 = bi0[2048 + h] + bh0[2048 + h];
        float bs3 = bi0[3072 + h] + bh0[3072 + h];
        #pragma unroll
        for (int q = 0; q < 4; ++q) {
          int brow = rt * 16 + g * 4 + q;
          size_t off = (size_t)brow * 1024 + h;
          size_t coff = (size_t)bid * 256 + (g * 4 + q) * 16 + r15;
          float iv = acc[0][q] + bs0, fv = acc[1][q] + bs1;
          float gv = acc[2][q] + bs2, ov = acc[3][q] + bs3;
          float cn = sigm(fv) * c0b[coff] + sigm(iv) * tanhf(gv);
          float hn = sigm(ov) * tanhf(cn);
          c0b[coff] = cn;                   // block-EXCLUSIVE tile: safe
          st16c(h0r + snxt + off, f2b(hn)); // ring slot t+1, write-once
        }
      }
      gbar(bar, bid, ++barno);
    }

    // ---- P2: LSTM1 gates (K=2048: h0[t+1] | h1[t]) ----
    {
      f4v acc[4] = {z, z, z, z};
      const short* wbase = W1p + (size_t)(cs * 16 + r15) * 32 + 4 * g;
      seg_gemm<4>(h0r + snxt, 1024, 32, h1r + scur, 1024, 32,
                  (const short*)nullptr, 0, 0,
                  wbase, (size_t)4096 * 32, w * 16, w * 16 + 16,
                  acc, rt * 16 + r15, g);
      wave_reduce<4>(acc, smem, w, l);
      if (w == 0) {
        int h = cs * 16 + r15;
        float bs0 = bi1[h] + bh1[h];
        float bs1 = bi1[1024 + h] + bh1[1024 + h];
        float bs2 = bi1[2048 + h] + bh1[2048 + h];
        float bs3 = bi1[3072 + h] + bh1[3072 + h];
        #pragma unroll
        for (int q = 0; q < 4; ++q) {
          int brow = rt * 16 + g * 4 + q;
          size_t off = (size_t)brow * 1024 + h;
          size_t coff = (size_t)bid * 256 + (g * 4 + q) * 16 + r15;
          float iv = acc[0][q] + bs0, fv = acc[1][q] + bs1;
          float gv = acc[2][q] + bs2, ov = acc[3][q] + bs3;
          float cn = sigm(fv) * c1b[coff] + sigm(iv) * tanhf(gv);
          float hn = sigm(ov) * tanhf(cn);
          c1b[coff] = cn;
          st16c(h1r + snxt + off, f2b(hn));
        }
      }
      gbar(bar, bid, ++barno);
    }

    // ---- P3: qproj (N=1024, K=1024) ----
    {
      f4v acc[1] = {z};
      const short* wbase = Wap + (size_t)(cs * 16 + r15) * 32 + 4 * g;
      seg_gemm<1>(h1r + snxt, 1024, 32, (const short*)nullptr, 0, 0,
                  (const short*)nullptr, 0, 0,
                  wbase, (size_t)1024 * 32, w * 8, w * 8 + 8,
                  acc, rt * 16 + r15, g);
      wave_reduce<1>(acc, smem, w, l);
      if (w == 0) {
        int nb = cs * 16 + r15;
        #pragma unroll
        for (int q = 0; q < 4; ++q) {
          int brow = rt * 16 + g * 4 + q;
          st16c(qb + (size_t)brow * 1024 + nb, f2b(acc[0][q]));
        }
      }
      gbar(bar, bid, ++barno);
    }

    // ---- P4: attention partial + fused merge (per-b local sync) ----
    {
      int b = bid & 63, chunk = bid >> 6;
      int s0 = chunk * 151;
      int send = 602 < s0 + 151 ? 602 : s0 + 151;
      const short* qp = qb + (size_t)b * 1024 + l * 16;
      float qf[16];
      #pragma unroll
      for (int c4 = 0; c4 < 4; ++c4) {
        U64S x; x.u = ld64c(qp + c4 * 4);
        #pragma unroll
        for (int j = 0; j < 4; ++j) qf[c4 * 4 + j] = b2f(x.s[j]);
      }
      float o[16];
      #pragma unroll
      for (int j = 0; j < 16; ++j) o[j] = 0.f;
      float ls8 = 0.f;
      // FOUR independent s-rows in flight per wave (s, s+4, s+8, s+12)
      for (int s = s0 + w; s < send; s += 16) {
        int sr[4] = {s, s + 4, s + 8, s + 12};
        bool has[4];
        #pragma unroll
        for (int r = 0; r < 4; ++r) has[r] = sr[r] < send;
        float mv[4][16];
        if (useMb) {
          #pragma unroll
          for (int r = 0; r < 4; ++r) {
            int sx = has[r] ? sr[r] : s;
            const short* mp = Mb + ((size_t)sx * 64 + b) * 1024 + l * 16;
            s8v a0 = *(const s8v*)mp, a1 = *(const s8v*)(mp + 8);
            #pragma unroll
            for (int j = 0; j < 8; ++j) {
              mv[r][j] = b2f(a0[j]); mv[r][8 + j] = b2f(a1[j]);
            }
          }
        } else {
          #pragma unroll
          for (int r = 0; r < 4; ++r) {
            int sx = has[r] ? sr[r] : s;
            const float* mp = memf + ((size_t)sx * 64 + b) * 1024 + l * 16;
            f4v a0 = *(const f4v*)mp, a1 = *(const f4v*)(mp + 4);
            f4v a2 = *(const f4v*)(mp + 8), a3 = *(const f4v*)(mp + 12);
            #pragma unroll
            for (int j = 0; j < 4; ++j) {
              mv[r][j] = a0[j]; mv[r][4 + j] = a1[j];
              mv[r][8 + j] = a2[j]; mv[r][12 + j] = a3[j];
            }
          }
        }
        float d[4] = {0.f, 0.f, 0.f, 0.f};
        #pragma unroll
        for (int j = 0; j < 16; ++j) {
          #pragma unroll
          for (int r = 0; r < 4; ++r) d[r] += qf[j] * mv[r][j];
        }
        #pragma unroll
        for (int off = 32; off; off >>= 1) {
          #pragma unroll
          for (int r = 0; r < 4; ++r) d[r] += __shfl_down(d[r], off);
        }
        float p[4];
        #pragma unroll
        for (int r = 0; r < 4; ++r) {
          d[r] = __shfl(d[r], 0);
          p[r] = has[r] ? __expf(fminf(d[r], 80.f) - 8.f) : 0.f;
          ls8 += p[r];
        }
        if (l == 0) {
          #pragma unroll
          for (int r = 0; r < 4; ++r)
            if (has[r]) stfc(alg + b * 602 + sr[r], p[r]);
        }
        #pragma unroll
        for (int j = 0; j < 16; ++j)
          o[j] += p[0] * mv[0][j] + p[1] * mv[1][j]
                + p[2] * mv[2][j] + p[3] * mv[3][j];
      }
      // ===== ABLATION PASS 2: identical stream+compute, no output writes.
      // Result kept alive via asm (no DCE); measures P4 marginal cost. =====
      {
        float o2[16];
        #pragma unroll
        for (int j = 0; j < 16; ++j) o2[j] = 0.f;
        for (int s = s0 + w; s < send; s += 16) {
          int sr[4] = {s, s + 4, s + 8, s + 12};
          bool has[4];
          #pragma unroll
          for (int r = 0; r < 4; ++r) has[r] = sr[r] < send;
          float mv[4][16];
          if (useMb) {
            #pragma unroll
            for (int r = 0; r < 4; ++r) {
              int sx = has[r] ? sr[r] : s;
              const short* mp = Mb + ((size_t)sx * 64 + b) * 1024 + l * 16;
              s8v a0 = *(const s8v*)mp, a1 = *(const s8v*)(mp + 8);
              #pragma unroll
              for (int j = 0; j < 8; ++j) {
                mv[r][j] = b2f(a0[j]); mv[r][8 + j] = b2f(a1[j]);
              }
            }
          } else {
            #pragma unroll
            for (int r = 0; r < 4; ++r) {
              int sx = has[r] ? sr[r] : s;
              const float* mp = memf + ((size_t)sx * 64 + b) * 1024 + l * 16;
              f4v a0 = *(const f4v*)mp, a1 = *(const f4v*)(mp + 4);
              f4v a2 = *(const f4v*)(mp + 8), a3 = *(const f4v*)(mp + 12);
              #pragma unroll
              for (int j = 0; j < 4; ++j) {
                mv[r][j] = a0[j]; mv[r][4 + j] = a1[j];
                mv[r][8 + j] = a2[j]; mv[r][12 + j] = a3[j];
              }
            }
          }
          float d[4] = {0.f, 0.f, 0.f, 0.f};
          #pragma unroll
          for (int j = 0; j < 16; ++j) {
            #pragma unroll
            for (int r = 0; r < 4; ++r) d[r] += qf[j] * mv[r][j];
          }
          #pragma unroll
          for (int off = 32; off; off >>= 1) {
            #pragma unroll
            for (int r = 0; r < 4; ++r) d[r] += __shfl_down(d[r], off);
          }
          float p[4];
          #pragma unroll
          for (int r = 0; r < 4; ++r) {
            d[r] = __shfl(d[r], 0);
            p[r] = has[r] ? __expf(fminf(d[r], 80.f) - 8.f) : 0.f;
          }
          #pragma unroll
          for (int j = 0; j < 16; ++j)
            o2[j] += p[0] * mv[0][j] + p[1] * mv[1][j]
                   + p[2] * mv[2][j] + p[3] * mv[3][j];
        }
        float s2 = 0.f;
        #pragma unroll
        for (int j = 0; j < 16; ++j) s2 += o2[j];
        asm volatile("" :: "v"(s2));      // keep pass-2 live, no side effect
      }
      float* pp = part + (size_t)(b * 16 + chunk * 4 + w) * 1024;
      #pragma unroll
      for (int j4 = 0; j4 < 8; ++j4) {
        U64F x; x.f[0] = o[j4 * 2]; x.f[1] = o[j4 * 2 + 1];
        st64c(pp + l * 16 + j4 * 2, x.u);
      }
      if (l == 0) smem[5120 + w] = ls8;
      __syncthreads();                    // drains part stores + ls8 to LDS
      if (tid == 0)
        stfc(csum + b * 4 + chunk,
             smem[5120] + smem[5121] + smem[5122] + smem[5123]);
      __syncthreads();                    // drains tid0's csum store
      // local per-b sync: all 4 sibling chunk-blocks arrived with partials
      if (tid == 0) {
        int* acnt = bar + 6144 + b * 16;
        __hip_atomic_fetch_add(acnt, 1, __ATOMIC_RELAXED,
                               __HIP_MEMORY_SCOPE_AGENT);
        while (__hip_atomic_load(acnt, __ATOMIC_RELAXED,
                                 __HIP_MEMORY_SCOPE_AGENT) < 4 * (t + 1))
          __builtin_amdgcn_s_sleep(1);
      }
      __syncthreads();
      // fused merge: fixed-shift softmax is exact (shift-invariant)
      {
        const float* cs4 = csum + b * 4;
        float L8 = ldfc(cs4) + ldfc(cs4 + 1) + ldfc(cs4 + 2) + ldfc(cs4 + 3);
        float invL = 1.f / L8;
        if (tid < 128) {                  // this block's 256 ctx cols
          int h = chunk * 256 + tid * 2;
          float a0 = 0.f, a1 = 0.f;
          #pragma unroll
          for (int p = 0; p < 16; ++p) {
            U64F x; x.u = ld64c(part + (size_t)(b * 16 + p) * 1024 + h);
            a0 += x.f[0]; a1 += x.f[1];
          }
          short* cp = ctxr + snxt + (size_t)b * 1024 + h;
          st16c(cp, f2b(a0 * invL));
          st16c(cp + 1, f2b(a1 * invL));
        }
        float* attns = out + 6553600 + (size_t)t * 64 * 602;
        for (int i = s0 + tid; i < send; i += 256)
          stfc(attns + b * 602 + i, ldfc(alg + b * 602 + i) * invL);
      }
      gbar(bar, bid, ++barno);
    }

    // ---- P6: out projection + tanh (N=1024, K=2048: ctx[t+1]|h1[t+1]) ----
    {
      f4v acc[1] = {z};
      const short* wbase = Wop + (size_t)(cs * 16 + r15) * 32 + 4 * g;
      seg_gemm<1>(ctxr + snxt, 1024, 32, h1r + snxt, 1024, 32,
                  (const short*)nullptr, 0, 0,
                  wbase, (size_t)1024 * 32, w * 16, w * 16 + 16,
                  acc, rt * 16 + r15, g);
      wave_reduce<1>(acc, smem, w, l);
      if (w == 0) {
        int nb = cs * 16 + r15;
        float* outp = out + (size_t)t * 65536;
        #pragma unroll
        for (int q = 0; q < 4; ++q) {
          int brow = rt * 16 + g * 4 + q;
          size_t off = (size_t)brow * 1024 + nb;
          float v = tanhf(acc[0][q]);
          stfc(outp + off, v);              // write-through: no false sharing
          st16c(feedr + snxt + off, f2b(v));
        }
      }
      gbar(bar, bid, ++barno);
    }
  }
}

// ---------------- launcher -------------------------------------------------

extern "C" void kernel_launch(void* const* d_in, const int* in_sizes, int n_in,
                              void* d_out, int out_size, void* d_ws, size_t ws_size,
                              hipStream_t stream) {
  const int*   tgt  = (const int*)  d_in[0];
  const float* mem  = (const float*)d_in[1];
  const float* h0   = (const float*)d_in[2];
  const float* c0   = (const float*)d_in[3];
  const float* embw = (const float*)d_in[4];
  const float* Wi0  = (const float*)d_in[5];
  const float* Wh0  = (const float*)d_in[6];
  const float* bi0  = (const float*)d_in[7];
  const float* bh0  = (const float*)d_in[8];
  const float* Wi1  = (const float*)d_in[9];
  const float* Wh1  = (const float*)d_in[10];
  const float* bi1  = (const float*)d_in[11];
  const float* bh1  = (const float*)d_in[12];
  const float* Wat  = (const float*)d_in[13];
  const float* Wou  = (const float*)d_in[14];
  float* out = (float*)d_out;

  char* base = (char*)d_ws;
  size_t off = 0;
  auto alloc = [&](size_t bytes) -> void* {
    void* p = base + off;
    off += (bytes + 255) & ~(size_t)255;
    return p;
  };
  const size_t RING = (size_t)101 * 65536;   // 101 slots x 64x1024 bf16
  int* bar = (int*)alloc(32768);   // slots + relay lines + attn counters
  short* qb   = (short*)alloc(65536 * 2);
  float* csum = (float*)alloc(64 * 4 * 4);
  float* c0b  = (float*)alloc(65536 * 4);
  float* c1b  = (float*)alloc(65536 * 4);
  float* alg  = (float*)alloc((size_t)64 * 602 * 4);
  float* part = (float*)alloc((size_t)64 * 16 * 1024 * 4);
  short* emba = (short*)alloc((size_t)100 * 64 * 512 * 2);
  short* Wap  = (short*)alloc((size_t)32 * 1024 * 32 * 2);
  short* Wop  = (short*)alloc((size_t)64 * 1024 * 32 * 2);
  short* W1p  = (short*)alloc((size_t)64 * 4096 * 32 * 2);
  short* W0p  = (short*)alloc((size_t)80 * 4096 * 32 * 2);
  short* h0r  = (short*)alloc(RING * 2);
  short* h1r  = (short*)alloc(RING * 2);
  short* feedr= (short*)alloc(RING * 2);
  short* ctxr = (short*)alloc(RING * 2);
  const size_t MBE = (size_t)602 * 64 * 1024;
  bool useMb = (off + MBE * 2 + 256) <= ws_size;
  short* Mb = useMb ? (short*)alloc(MBE * 2) : nullptr;

  hipMemsetAsync(bar, 0, 32768, stream);
  hipLaunchKernelGGL(emb_gather, dim3(6400), dim3(64), 0, stream, tgt, embw, emba);
  hipLaunchKernelGGL(pack_w, dim3(2048), dim3(256), 0, stream, Wi0, 1536, Wh0, 1024,
                     W0p, 4096, (long)80 * 4096 * 4);
  hipLaunchKernelGGL(pack_w, dim3(2048), dim3(256), 0, stream, Wi1, 1024, Wh1, 1024,
                     W1p, 4096, (long)64 * 4096 * 4);
  hipLaunchKernelGGL(pack_w, dim3(1024), dim3(256), 0, stream, Wou, 2048, Wou, 2048,
                     Wop, 1024, (long)64 * 1024 * 4);
  hipLaunchKernelGGL(pack_w, dim3(512), dim3(256), 0, stream, Wat, 1024, Wat, 1024,
                     Wap, 1024, (long)32 * 1024 * 4);
  hipLaunchKernelGGL(init_state, dim3(256), dim3(256), 0, stream, h0, c0,
                     h0r, h1r, c0b, c1b, feedr);
  if (useMb)
    hipLaunchKernelGGL(cvt_bf16, dim3(2048), dim3(256), 0, stream, mem, Mb,
                       (long)(MBE / 8));

  hipLaunchKernelGGL(decoder_k, dim3(256), dim3(256), 0, stream,
                     W0p, W1p, Wop, Wap, emba,
                     bi0, bh0, bi1, bh1,
                     h0r, h1r, feedr, ctxr, qb,
                     c0b, c1b, alg, part, csum,
                     Mb, mem, out, (int)useMb,
                     bar);
}

// Round 17
// 7352.503 us; speedup vs baseline: 1.1825x; 1.1825x over previous
//
#include <hip/hip_runtime.h>

// InputFeedRNNDecoder on MI355X.  T=100 B=64 S=602 H=1024 E=512 V=10000.
// Persistent kernel: 256 blocks x 256 threads (1 block/CU, 4 waves), 100
// steps. SYNC = dependency-exact per-group store-slot counters (64-block
// row-groups for GEMM phases, 4-block sibling groups for attention) --
// no global barrier, no monitor, groups pipeline independently.
// Coherence: mutable state in 101-deep WRITE-ONCE ring buffers -> producers
// use sc0sc1 write-through stores, consumers use NORMAL CACHED loads.
// c-state in block-exclusive tiles; out/attns write-through (no false share).
// GEMM: direct cached global A-fragment loads, 4-way k-split, LDS reduce.
// Attention: fixed-shift exact softmax; 4-deep row pipeline in P4.

#define DI __device__ __forceinline__

typedef __attribute__((ext_vector_type(4))) short s4v;
typedef __attribute__((ext_vector_type(8))) short s8v;
typedef __attribute__((ext_vector_type(4))) float f4v;

DI float b2f(short u) {
  unsigned int x = ((unsigned int)(unsigned short)u) << 16;
  float f; __builtin_memcpy(&f, &x, 4); return f;
}
DI short f2b(float f) {  // round-to-nearest-even
  unsigned int x; __builtin_memcpy(&x, &f, 4);
  return (short)((x + 0x7fffu + ((x >> 16) & 1u)) >> 16);
}
DI s8v cat8(s4v lo, s4v hi) {
  s8v r; r[0]=lo[0];r[1]=lo[1];r[2]=lo[2];r[3]=lo[3];
  r[4]=hi[0];r[5]=hi[1];r[6]=hi[2];r[7]=hi[3]; return r;
}
DI f4v mfma16(s8v a, s8v b, f4v c) {
  return __builtin_amdgcn_mfma_f32_16x16x32_bf16(a, b, c, 0, 0, 0);
}
DI float sigm(float x) { return 1.f / (1.f + __expf(-x)); }

// ---- coherent access helpers (system scope, cache-bypassing) --------------
DI unsigned long long ld64c(const void* p) {
  return __hip_atomic_load((const unsigned long long*)p, __ATOMIC_RELAXED,
                           __HIP_MEMORY_SCOPE_SYSTEM);
}
DI void st64c(void* p, unsigned long long v) {
  __hip_atomic_store((unsigned long long*)p, v, __ATOMIC_RELAXED,
                     __HIP_MEMORY_SCOPE_SYSTEM);
}
DI float ldfc(const float* p) {
  return __hip_atomic_load(p, __ATOMIC_RELAXED, __HIP_MEMORY_SCOPE_SYSTEM);
}
DI void stfc(float* p, float v) {
  __hip_atomic_store(p, v, __ATOMIC_RELAXED, __HIP_MEMORY_SCOPE_SYSTEM);
}
DI int ld32c(const int* p) {
  return __hip_atomic_load(p, __ATOMIC_RELAXED, __HIP_MEMORY_SCOPE_SYSTEM);
}
DI void st32c(int* p, int v) {
  __hip_atomic_store(p, v, __ATOMIC_RELAXED, __HIP_MEMORY_SCOPE_SYSTEM);
}
DI void st16c(short* p, short v) {    // 16-bit write-through store
  asm volatile("global_store_short %0, %1, off sc0 sc1"
               :: "v"(p), "v"((unsigned int)(unsigned short)v) : "memory");
}
union U64S { unsigned long long u; short s[4]; };
union U64F { unsigned long long u; float f[2]; };

// ---------------- packing kernels (run once per call) ----------------------

__global__ void cvt_bf16(const float* __restrict__ src, short* __restrict__ dst, long n8) {
  long i = (long)blockIdx.x * blockDim.x + threadIdx.x;
  long stride = (long)gridDim.x * blockDim.x;
  for (; i < n8; i += stride) {
    const float* s = src + i * 8;
    s8v o;
    #pragma unroll
    for (int j = 0; j < 8; ++j) o[j] = f2b(s[j]);
    *(s8v*)(dst + i * 8) = o;
  }
}

// dst[(kt*N + n)*32 + k32] = W[n][kt*32+k32]  with W = [WA | WB] along k.
__global__ void pack_w(const float* __restrict__ WA, int Ka,
                       const float* __restrict__ WB, int Kb,
                       short* __restrict__ dst, int N, long total) {
  long i = (long)blockIdx.x * blockDim.x + threadIdx.x;
  long stride = (long)gridDim.x * blockDim.x;
  for (; i < total; i += stride) {
    int c = (int)(i & 3);
    long r = i >> 2;
    int n = (int)(r % N);
    int kt = (int)(r / N);
    int k = kt * 32 + c * 8;
    const float* s = (k < Ka) ? (WA + (size_t)n * Ka + k)
                              : (WB + (size_t)n * Kb + (k - Ka));
    s8v o;
    #pragma unroll
    for (int j = 0; j < 8; ++j) o[j] = f2b(s[j]);
    *(s8v*)(dst + r * 32 + c * 8) = o;
  }
}

__global__ __launch_bounds__(64) void emb_gather(const int* __restrict__ tgt,
                                                 const float* __restrict__ emb,
                                                 short* __restrict__ dst) {
  int tb = blockIdx.x;                // 0..6399 = t*64+b
  int idx = tgt[tb];
  const float* s = emb + (size_t)idx * 512 + threadIdx.x * 8;
  s8v o;
  #pragma unroll
  for (int j = 0; j < 8; ++j) o[j] = f2b(s[j]);
  *(s8v*)(dst + (size_t)tb * 512 + threadIdx.x * 8) = o;
}

// c-state tile layout: c[bid*256 + lr*16 + lc], bid = (row>>4)*64 + (col>>4),
// lr = row&15, lc = col&15  -> every 1KB tile is exclusively one block's.
__global__ void init_state(const float* __restrict__ h0, const float* __restrict__ c0,
                           short* __restrict__ h0r, short* __restrict__ h1r,
                           float* __restrict__ c0buf, float* __restrict__ c1buf,
                           short* __restrict__ feedr) {
  int i = blockIdx.x * 256 + threadIdx.x;
  if (i < 65536) {
    h0r[i] = f2b(h0[i]);          // ring slot 0
    h1r[i] = f2b(h0[65536 + i]);
    int row = i >> 10, col = i & 1023;
    size_t coff = (size_t)((row >> 4) * 64 + (col >> 4)) * 256
                + (row & 15) * 16 + (col & 15);
    c0buf[coff] = c0[i];
    c1buf[coff] = c0[65536 + i];
    feedr[i] = 0;                 // bf16 zero, slot 0
  }
}

// ---------------- GEMM core: direct cached global A loads ------------------

template <int NG>
DI void kloop(const short* __restrict__ A, int ld, int nkt,
              const short* __restrict__ Wp, size_t wkt,
              f4v* acc, int rA, int g) {
  if (nkt <= 0) return;
  const short* ap = A + (size_t)rA * ld + 4 * g;
  s4v alo = *(const s4v*)ap, ahi = *(const s4v*)(ap + 16);
  s4v blo[NG], bhi[NG];
  #pragma unroll
  for (int t = 0; t < NG; ++t) {
    blo[t] = *(const s4v*)(Wp + (size_t)t * 32768);
    bhi[t] = *(const s4v*)(Wp + (size_t)t * 32768 + 16);
  }
  for (int kt = 0; kt < nkt - 1; ++kt) {
    const short* apn = ap + (kt + 1) * 32;
    const short* bpn = Wp + (size_t)(kt + 1) * wkt;
    s4v nalo = *(const s4v*)apn, nahi = *(const s4v*)(apn + 16);
    s4v nblo[NG], nbhi[NG];
    #pragma unroll
    for (int t = 0; t < NG; ++t) {
      nblo[t] = *(const s4v*)(bpn + (size_t)t * 32768);
      nbhi[t] = *(const s4v*)(bpn + (size_t)t * 32768 + 16);
    }
    s8v a = cat8(alo, ahi);
    #pragma unroll
    for (int t = 0; t < NG; ++t) acc[t] = mfma16(a, cat8(blo[t], bhi[t]), acc[t]);
    alo = nalo; ahi = nahi;
    #pragma unroll
    for (int t = 0; t < NG; ++t) { blo[t] = nblo[t]; bhi[t] = nbhi[t]; }
  }
  s8v a = cat8(alo, ahi);
  #pragma unroll
  for (int t = 0; t < NG; ++t) acc[t] = mfma16(a, cat8(blo[t], bhi[t]), acc[t]);
}

// Up to 3 K-segments; this wave covers global k-tiles [k0,k1).
template <int NG>
DI void seg_gemm(const short* __restrict__ A0, int ld0, int n0,
                 const short* __restrict__ A1, int ld1, int n1,
                 const short* __restrict__ A2, int ld2, int n2,
                 const short* __restrict__ wbase, size_t wkt,
                 int k0, int k1, f4v* acc, int rA, int g) {
  int s = 0;
  {
    int a = k0 > s ? k0 : s, b = k1 < (s + n0) ? k1 : (s + n0);
    if (a < b) kloop<NG>(A0 + (size_t)(a - s) * 32, ld0, b - a,
                         wbase + (size_t)a * wkt, wkt, acc, rA, g);
    s += n0;
  }
  {
    int a = k0 > s ? k0 : s, b = k1 < (s + n1) ? k1 : (s + n1);
    if (a < b) kloop<NG>(A1 + (size_t)(a - s) * 32, ld1, b - a,
                         wbase + (size_t)a * wkt, wkt, acc, rA, g);
    s += n1;
  }
  if (n2 > 0) {
    int a = k0 > s ? k0 : s, b = k1 < (s + n2) ? k1 : (s + n2);
    if (a < b) kloop<NG>(A2 + (size_t)(a - s) * 32, ld2, b - a,
                         wbase + (size_t)a * wkt, wkt, acc, rA, g);
  }
}

// Sum the 4 waves' partial accumulators via LDS. Wave 0 holds the total.
template <int NG>
DI void wave_reduce(f4v* acc, float* smem, int w, int l) {
  #pragma unroll
  for (int t4 = 0; t4 < NG; ++t4)
    *(f4v*)&smem[(w * 64 + l) * 20 + t4 * 4] = acc[t4];
  __syncthreads();
  if (w == 0) {
    #pragma unroll
    for (int t4 = 0; t4 < NG; ++t4) {
      f4v s0 = *(f4v*)&smem[l * 20 + t4 * 4];
      #pragma unroll
      for (int ww = 1; ww < 4; ++ww) {
        f4v v = *(f4v*)&smem[(ww * 64 + l) * 20 + t4 * 4];
        #pragma unroll
        for (int j = 0; j < 4; ++j) s0[j] += v[j];
      }
      acc[t4] = s0;
    }
  }
}

// ---- dependency-exact group sync: store-slot counters ---------------------
// Slots are 16-int (64B) strided, monotonic (posted value = t+1).
// Arrays (offsets in ints, each 256 slots = 4096 ints):
//   s_p1 @ 0, s_p2 @ 4096, s_p3 @ 8192, s_p6 @ 12288   [slot rt*64+cs]
//   s_p4 @ 16384, s_mg @ 20480                          [slot b*4+chunk]

DI void post(int* slot, int val) {   // call AFTER a draining __syncthreads
  if (threadIdx.x == 0) st32c(slot, val);
}
DI void wait64(const int* slots, int want) {   // 64 producer slots
  for (;;) {
    int ok = 1;
    if (threadIdx.x < 64) ok = (ld32c(slots + threadIdx.x * 16) >= want);
    if (__syncthreads_and(ok)) break;
    __builtin_amdgcn_s_sleep(4);
  }
}
DI void wait4(const int* slots, int want) {    // 4 sibling slots
  for (;;) {
    int ok = 1;
    if (threadIdx.x < 4) ok = (ld32c(slots + threadIdx.x * 16) >= want);
    if (__syncthreads_and(ok)) break;
    __builtin_amdgcn_s_sleep(2);
  }
}

// ---------------- the persistent decoder kernel ----------------------------

__global__ __launch_bounds__(256, 1) void decoder_k(
    const short* __restrict__ W0p, const short* __restrict__ W1p,
    const short* __restrict__ Wop, const short* __restrict__ Wap,
    const short* __restrict__ emba,
    const float* __restrict__ bi0, const float* __restrict__ bh0,
    const float* __restrict__ bi1, const float* __restrict__ bh1,
    short* h0r, short* h1r, short* feedr, short* ctxr, short* qb,
    float* c0b, float* c1b, float* alg, float* part, float* csum,
    const short* __restrict__ Mb, const float* __restrict__ memf,
    float* out, int useMb, int* bar) {
  __shared__ float smem[5248];
  const int bid = blockIdx.x, tid = threadIdx.x;
  const int w = tid >> 6, l = tid & 63, r15 = l & 15, g = l >> 4;
  // XCD-colocating remap: the 4 blocks sharing a weight slice (same cs) are
  // bid = cs + {0,64,128,192} == cs (mod 8) -> same XCD under round-robin.
  const int cs = bid & 63, rt = bid >> 6;
  const int b = bid & 63, chunk = bid >> 6;        // attention role
  int* s_p1 = bar;
  int* s_p2 = bar + 4096;
  int* s_p3 = bar + 8192;
  int* s_p6 = bar + 12288;
  int* s_p4 = bar + 16384;
  int* s_mg = bar + 20480;
  int* my_gemm_slot = bar /*array chosen per phase*/;
  f4v z = {0.f, 0.f, 0.f, 0.f};
  (void)my_gemm_slot;

  for (int t = 0; t < 100; ++t) {
    const size_t scur = (size_t)t * 65536, snxt = (size_t)(t + 1) * 65536;

    // ---- P1: LSTM0 gates (N=4096, K=2560: emb512|feed1024|h0 1024) ----
    {
      wait64(s_p6 + rt * 1024, t);          // feed[t] rows rt*16 ready
      f4v acc[4] = {z, z, z, z};
      const short* wbase = W0p + (size_t)(cs * 16 + r15) * 32 + 4 * g;
      seg_gemm<4>(emba + (size_t)t * 64 * 512, 512, 16,
                  feedr + scur, 1024, 32, h0r + scur, 1024, 32,
                  wbase, (size_t)4096 * 32, w * 20, w * 20 + 20,
                  acc, rt * 16 + r15, g);
      wave_reduce<4>(acc, smem, w, l);
      if (w == 0) {
        int h = cs * 16 + r15;
        float bs0 = bi0[h] + bh0[h];
        float bs1 = bi0[1024 + h] + bh0[1024 + h];
        float bs2 = bi0[2048 + h] + bh0[2048 + h];
        float bs3 = bi0[3072 + h] + bh0[3072 + h];
        #pragma unroll
        for (int q = 0; q < 4; ++q) {
          int brow = rt * 16 + g * 4 + q;
          size_t off = (size_t)brow * 1024 + h;
          size_t coff = (size_t)bid * 256 + (g * 4 + q) * 16 + r15;
          float iv = acc[0][q] + bs0, fv = acc[1][q] + bs1;
          float gv = acc[2][q] + bs2, ov = acc[3][q] + bs3;
          float cn = sigm(fv) * c0b[coff] + sigm(iv) * tanhf(gv);
          float hn = sigm(ov) * tanhf(cn);
          c0b[coff] = cn;                   // block-EXCLUSIVE tile: safe
          st16c(h0r + snxt + off, f2b(hn)); // ring slot t+1, write-once
        }
      }
      __syncthreads();                      // drain epilogue stores
      post(s_p1 + (rt * 64 + cs) * 16, t + 1);
    }

    // ---- P2: LSTM1 gates (K=2048: h0[t+1] | h1[t]) ----
    {
      wait64(s_p1 + rt * 1024, t + 1);      // h0[t+1] rows rt*16 ready
      f4v acc[4] = {z, z, z, z};
      const short* wbase = W1p + (size_t)(cs * 16 + r15) * 32 + 4 * g;
      seg_gemm<4>(h0r + snxt, 1024, 32, h1r + scur, 1024, 32,
                  (const short*)nullptr, 0, 0,
                  wbase, (size_t)4096 * 32, w * 16, w * 16 + 16,
                  acc, rt * 16 + r15, g);
      wave_reduce<4>(acc, smem, w, l);
      if (w == 0) {
        int h = cs * 16 + r15;
        float bs0 = bi1[h] + bh1[h];
        float bs1 = bi1[1024 + h] + bh1[1024 + h];
        float bs2 = bi1[2048 + h] + bh1[2048 + h];
        float bs3 = bi1[3072 + h] + bh1[3072 + h];
        #pragma unroll
        for (int q = 0; q < 4; ++q) {
          int brow = rt * 16 + g * 4 + q;
          size_t off = (size_t)brow * 1024 + h;
          size_t coff = (size_t)bid * 256 + (g * 4 + q) * 16 + r15;
          float iv = acc[0][q] + bs0, fv = acc[1][q] + bs1;
          float gv = acc[2][q] + bs2, ov = acc[3][q] + bs3;
          float cn = sigm(fv) * c1b[coff] + sigm(iv) * tanhf(gv);
          float hn = sigm(ov) * tanhf(cn);
          c1b[coff] = cn;
          st16c(h1r + snxt + off, f2b(hn));
        }
      }
      __syncthreads();
      post(s_p2 + (rt * 64 + cs) * 16, t + 1);
    }

    // ---- P3: qproj (N=1024, K=1024) ----
    {
      wait64(s_p2 + rt * 1024, t + 1);      // h1[t+1] rows rt*16 ready
      f4v acc[1] = {z};
      const short* wbase = Wap + (size_t)(cs * 16 + r15) * 32 + 4 * g;
      seg_gemm<1>(h1r + snxt, 1024, 32, (const short*)nullptr, 0, 0,
                  (const short*)nullptr, 0, 0,
                  wbase, (size_t)1024 * 32, w * 8, w * 8 + 8,
                  acc, rt * 16 + r15, g);
      wave_reduce<1>(acc, smem, w, l);
      if (w == 0) {
        int nb = cs * 16 + r15;
        #pragma unroll
        for (int q = 0; q < 4; ++q) {
          int brow = rt * 16 + g * 4 + q;
          st16c(qb + (size_t)brow * 1024 + nb, f2b(acc[0][q]));
        }
      }
      __syncthreads();
      post(s_p3 + (rt * 64 + cs) * 16, t + 1);
    }

    // ---- P4: attention partial + fused merge (group-local sync) ----
    {
      wait64(s_p3 + (b >> 4) * 1024, t + 1); // q row b ready (group b>>4)
      wait4(s_mg + b * 64, t);               // WAR: prev merge reads done
      int s0 = chunk * 151;
      int send = 602 < s0 + 151 ? 602 : s0 + 151;
      const short* qp = qb + (size_t)b * 1024 + l * 16;
      float qf[16];
      #pragma unroll
      for (int c4 = 0; c4 < 4; ++c4) {
        U64S x; x.u = ld64c(qp + c4 * 4);
        #pragma unroll
        for (int j = 0; j < 4; ++j) qf[c4 * 4 + j] = b2f(x.s[j]);
      }
      float o[16];
      #pragma unroll
      for (int j = 0; j < 16; ++j) o[j] = 0.f;
      float ls8 = 0.f;
      // FOUR independent s-rows in flight per wave (s, s+4, s+8, s+12)
      for (int s = s0 + w; s < send; s += 16) {
        int sr[4] = {s, s + 4, s + 8, s + 12};
        bool has[4];
        #pragma unroll
        for (int r = 0; r < 4; ++r) has[r] = sr[r] < send;
        float mv[4][16];
        if (useMb) {
          #pragma unroll
          for (int r = 0; r < 4; ++r) {
            int sx = has[r] ? sr[r] : s;
            const short* mp = Mb + ((size_t)sx * 64 + b) * 1024 + l * 16;
            s8v a0 = *(const s8v*)mp, a1 = *(const s8v*)(mp + 8);
            #pragma unroll
            for (int j = 0; j < 8; ++j) {
              mv[r][j] = b2f(a0[j]); mv[r][8 + j] = b2f(a1[j]);
            }
          }
        } else {
          #pragma unroll
          for (int r = 0; r < 4; ++r) {
            int sx = has[r] ? sr[r] : s;
            const float* mp = memf + ((size_t)sx * 64 + b) * 1024 + l * 16;
            f4v a0 = *(const f4v*)mp, a1 = *(const f4v*)(mp + 4);
            f4v a2 = *(const f4v*)(mp + 8), a3 = *(const f4v*)(mp + 12);
            #pragma unroll
            for (int j = 0; j < 4; ++j) {
              mv[r][j] = a0[j]; mv[r][4 + j] = a1[j];
              mv[r][8 + j] = a2[j]; mv[r][12 + j] = a3[j];
            }
          }
        }
        float d[4] = {0.f, 0.f, 0.f, 0.f};
        #pragma unroll
        for (int j = 0; j < 16; ++j) {
          #pragma unroll
          for (int r = 0; r < 4; ++r) d[r] += qf[j] * mv[r][j];
        }
        #pragma unroll
        for (int off = 32; off; off >>= 1) {
          #pragma unroll
          for (int r = 0; r < 4; ++r) d[r] += __shfl_down(d[r], off);
        }
        float p[4];
        #pragma unroll
        for (int r = 0; r < 4; ++r) {
          d[r] = __shfl(d[r], 0);
          p[r] = has[r] ? __expf(fminf(d[r], 80.f) - 8.f) : 0.f;
          ls8 += p[r];
        }
        if (l == 0) {
          #pragma unroll
          for (int r = 0; r < 4; ++r)
            if (has[r]) stfc(alg + b * 602 + sr[r], p[r]);
        }
        #pragma unroll
        for (int j = 0; j < 16; ++j)
          o[j] += p[0] * mv[0][j] + p[1] * mv[1][j]
                + p[2] * mv[2][j] + p[3] * mv[3][j];
      }
      float* pp = part + (size_t)(b * 16 + chunk * 4 + w) * 1024;
      #pragma unroll
      for (int j4 = 0; j4 < 8; ++j4) {
        U64F x; x.f[0] = o[j4 * 2]; x.f[1] = o[j4 * 2 + 1];
        st64c(pp + l * 16 + j4 * 2, x.u);
      }
      if (l == 0) smem[5120 + w] = ls8;
      __syncthreads();                    // drains part stores + ls8 to LDS
      if (tid == 0)
        stfc(csum + b * 4 + chunk,
             smem[5120] + smem[5121] + smem[5122] + smem[5123]);
      __syncthreads();                    // drains tid0's csum store
      post(s_p4 + (b * 4 + chunk) * 16, t + 1);
      wait4(s_p4 + b * 64, t + 1);        // siblings' partials ready
      // fused merge: fixed-shift softmax is exact (shift-invariant)
      {
        const float* cs4 = csum + b * 4;
        float L8 = ldfc(cs4) + ldfc(cs4 + 1) + ldfc(cs4 + 2) + ldfc(cs4 + 3);
        float invL = 1.f / L8;
        if (tid < 128) {                  // this block's 256 ctx cols
          int h = chunk * 256 + tid * 2;
          float a0 = 0.f, a1 = 0.f;
          #pragma unroll
          for (int p = 0; p < 16; ++p) {
            U64F x; x.u = ld64c(part + (size_t)(b * 16 + p) * 1024 + h);
            a0 += x.f[0]; a1 += x.f[1];
          }
          short* cp = ctxr + snxt + (size_t)b * 1024 + h;
          st16c(cp, f2b(a0 * invL));
          st16c(cp + 1, f2b(a1 * invL));
        }
        float* attns = out + 6553600 + (size_t)t * 64 * 602;
        for (int i = s0 + tid; i < send; i += 256)
          stfc(attns + b * 602 + i, ldfc(alg + b * 602 + i) * invL);
      }
      __syncthreads();                    // drain ctx/attns + part reads done
      post(s_mg + (b * 4 + chunk) * 16, t + 1);
    }

    // ---- P6: out projection + tanh (N=1024, K=2048: ctx[t+1]|h1[t+1]) ----
    {
      wait64(s_mg + rt * 1024, t + 1);    // ctx rows rt*16 ready
      f4v acc[1] = {z};
      const short* wbase = Wop + (size_t)(cs * 16 + r15) * 32 + 4 * g;
      seg_gemm<1>(ctxr + snxt, 1024, 32, h1r + snxt, 1024, 32,
                  (const short*)nullptr, 0, 0,
                  wbase, (size_t)1024 * 32, w * 16, w * 16 + 16,
                  acc, rt * 16 + r15, g);
      wave_reduce<1>(acc, smem, w, l);
      if (w == 0) {
        int nb = cs * 16 + r15;
        float* outp = out + (size_t)t * 65536;
        #pragma unroll
        for (int q = 0; q < 4; ++q) {
          int brow = rt * 16 + g * 4 + q;
          size_t off = (size_t)brow * 1024 + nb;
          float v = tanhf(acc[0][q]);
          stfc(outp + off, v);              // write-through: no false sharing
          st16c(feedr + snxt + off, f2b(v));
        }
      }
      __syncthreads();
      post(s_p6 + (rt * 64 + cs) * 16, t + 1);
    }
  }
}

// ---------------- launcher -------------------------------------------------

extern "C" void kernel_launch(void* const* d_in, const int* in_sizes, int n_in,
                              void* d_out, int out_size, void* d_ws, size_t ws_size,
                              hipStream_t stream) {
  const int*   tgt  = (const int*)  d_in[0];
  const float* mem  = (const float*)d_in[1];
  const float* h0   = (const float*)d_in[2];
  const float* c0   = (const float*)d_in[3];
  const float* embw = (const float*)d_in[4];
  const float* Wi0  = (const float*)d_in[5];
  const float* Wh0  = (const float*)d_in[6];
  const float* bi0  = (const float*)d_in[7];
  const float* bh0  = (const float*)d_in[8];
  const float* Wi1  = (const float*)d_in[9];
  const float* Wh1  = (const float*)d_in[10];
  const float* bi1  = (const float*)d_in[11];
  const float* bh1  = (const float*)d_in[12];
  const float* Wat  = (const float*)d_in[13];
  const float* Wou  = (const float*)d_in[14];
  float* out = (float*)d_out;

  char* base = (char*)d_ws;
  size_t off = 0;
  auto alloc = [&](size_t bytes) -> void* {
    void* p = base + off;
    off += (bytes + 255) & ~(size_t)255;
    return p;
  };
  const size_t RING = (size_t)101 * 65536;   // 101 slots x 64x1024 bf16
  int* bar = (int*)alloc(131072);  // 6 x 256 sync slots (64B strided)
  short* qb   = (short*)alloc(65536 * 2);
  float* csum = (float*)alloc(64 * 4 * 4);
  float* c0b  = (float*)alloc(65536 * 4);
  float* c1b  = (float*)alloc(65536 * 4);
  float* alg  = (float*)alloc((size_t)64 * 602 * 4);
  float* part = (float*)alloc((size_t)64 * 16 * 1024 * 4);
  short* emba = (short*)alloc((size_t)100 * 64 * 512 * 2);
  short* Wap  = (short*)alloc((size_t)32 * 1024 * 32 * 2);
  short* Wop  = (short*)alloc((size_t)64 * 1024 * 32 * 2);
  short* W1p  = (short*)alloc((size_t)64 * 4096 * 32 * 2);
  short* W0p  = (short*)alloc((size_t)80 * 4096 * 32 * 2);
  short* h0r  = (short*)alloc(RING * 2);
  short* h1r  = (short*)alloc(RING * 2);
  short* feedr= (short*)alloc(RING * 2);
  short* ctxr = (short*)alloc(RING * 2);
  const size_t MBE = (size_t)602 * 64 * 1024;
  bool useMb = (off + MBE * 2 + 256) <= ws_size;
  short* Mb = useMb ? (short*)alloc(MBE * 2) : nullptr;

  hipMemsetAsync(bar, 0, 131072, stream);
  hipLaunchKernelGGL(emb_gather, dim3(6400), dim3(64), 0, stream, tgt, embw, emba);
  hipLaunchKernelGGL(pack_w, dim3(2048), dim3(256), 0, stream, Wi0, 1536, Wh0, 1024,
                     W0p, 4096, (long)80 * 4096 * 4);
  hipLaunchKernelGGL(pack_w, dim3(2048), dim3(256), 0, stream, Wi1, 1024, Wh1, 1024,
                     W1p, 4096, (long)64 * 4096 * 4);
  hipLaunchKernelGGL(pack_w, dim3(1024), dim3(256), 0, stream, Wou, 2048, Wou, 2048,
                     Wop, 1024, (long)64 * 1024 * 4);
  hipLaunchKernelGGL(pack_w, dim3(512), dim3(256), 0, stream, Wat, 1024, Wat, 1024,
                     Wap, 1024, (long)32 * 1024 * 4);
  hipLaunchKernelGGL(init_state, dim3(256), dim3(256), 0, stream, h0, c0,
                     h0r, h1r, c0b, c1b, feedr);
  if (useMb)
    hipLaunchKernelGGL(cvt_bf16, dim3(2048), dim3(256), 0, stream, mem, Mb,
                       (long)(MBE / 8));

  hipLaunchKernelGGL(decoder_k, dim3(256), dim3(256), 0, stream,
                     W0p, W1p, Wop, Wap, emba,
                     bi0, bh0, bi1, bh1,
                     h0r, h1r, feedr, ctxr, qb,
                     c0b, c1b, alg, part, csum,
                     Mb, mem, out, (int)useMb,
                     bar);
}

// Round 18
// 7305.795 us; speedup vs baseline: 1.1901x; 1.0064x over previous
//
#include <hip/hip_runtime.h>

// InputFeedRNNDecoder on MI355X.  T=100 B=64 S=602 H=1024 E=512 V=10000.
// Persistent kernel: 256 blocks x 256 threads (1 block/CU, 4 waves), 100
// steps. SYNC = dependency-exact per-group store-slot counters (r17).
// GEMM: DUAL-CHAIN interleaved k-loop (2 independent load+MFMA chains per
// wave -> latency overlap, ~2x pipeline depth), direct cached A loads.
// Epilogues: results staged in LDS tile, emitted as 16B sc0sc1 dwordx4
// stores (32 acks vs 256 2B-store acks -> faster drain before post).
// Coherence: write-once rings (sc stores / cached loads); c-state block-
// exclusive; out/attns write-through. Attention: fixed-shift softmax,
// 4-deep row pipeline.

#define DI __device__ __forceinline__

typedef __attribute__((ext_vector_type(4))) short s4v;
typedef __attribute__((ext_vector_type(8))) short s8v;
typedef __attribute__((ext_vector_type(4))) float f4v;

DI float b2f(short u) {
  unsigned int x = ((unsigned int)(unsigned short)u) << 16;
  float f; __builtin_memcpy(&f, &x, 4); return f;
}
DI short f2b(float f) {  // round-to-nearest-even
  unsigned int x; __builtin_memcpy(&x, &f, 4);
  return (short)((x + 0x7fffu + ((x >> 16) & 1u)) >> 16);
}
DI s8v cat8(s4v lo, s4v hi) {
  s8v r; r[0]=lo[0];r[1]=lo[1];r[2]=lo[2];r[3]=lo[3];
  r[4]=hi[0];r[5]=hi[1];r[6]=hi[2];r[7]=hi[3]; return r;
}
DI f4v mfma16(s8v a, s8v b, f4v c) {
  return __builtin_amdgcn_mfma_f32_16x16x32_bf16(a, b, c, 0, 0, 0);
}
DI float sigm(float x) { return 1.f / (1.f + __expf(-x)); }

// ---- coherent access helpers (system scope, cache-bypassing) --------------
DI unsigned long long ld64c(const void* p) {
  return __hip_atomic_load((const unsigned long long*)p, __ATOMIC_RELAXED,
                           __HIP_MEMORY_SCOPE_SYSTEM);
}
DI void st64c(void* p, unsigned long long v) {
  __hip_atomic_store((unsigned long long*)p, v, __ATOMIC_RELAXED,
                     __HIP_MEMORY_SCOPE_SYSTEM);
}
DI float ldfc(const float* p) {
  return __hip_atomic_load(p, __ATOMIC_RELAXED, __HIP_MEMORY_SCOPE_SYSTEM);
}
DI void stfc(float* p, float v) {
  __hip_atomic_store(p, v, __ATOMIC_RELAXED, __HIP_MEMORY_SCOPE_SYSTEM);
}
DI int ld32c(const int* p) {
  return __hip_atomic_load(p, __ATOMIC_RELAXED, __HIP_MEMORY_SCOPE_SYSTEM);
}
DI void st32c(int* p, int v) {
  __hip_atomic_store(p, v, __ATOMIC_RELAXED, __HIP_MEMORY_SCOPE_SYSTEM);
}
DI void st16c(short* p, short v) {    // 16-bit write-through store
  asm volatile("global_store_short %0, %1, off sc0 sc1"
               :: "v"(p), "v"((unsigned int)(unsigned short)v) : "memory");
}
DI void st128c(void* p, s8v v) {      // 16B write-through store
  asm volatile("global_store_dwordx4 %0, %1, off sc0 sc1"
               :: "v"(p), "v"(v) : "memory");
}
DI void st128cf(void* p, f4v v) {     // 16B write-through store (f32x4)
  asm volatile("global_store_dwordx4 %0, %1, off sc0 sc1"
               :: "v"(p), "v"(v) : "memory");
}
union U64S { unsigned long long u; short s[4]; };
union U64F { unsigned long long u; float f[2]; };

// ---------------- packing kernels (run once per call) ----------------------

__global__ void cvt_bf16(const float* __restrict__ src, short* __restrict__ dst, long n8) {
  long i = (long)blockIdx.x * blockDim.x + threadIdx.x;
  long stride = (long)gridDim.x * blockDim.x;
  for (; i < n8; i += stride) {
    const float* s = src + i * 8;
    s8v o;
    #pragma unroll
    for (int j = 0; j < 8; ++j) o[j] = f2b(s[j]);
    *(s8v*)(dst + i * 8) = o;
  }
}

// dst[(kt*N + n)*32 + k32] = W[n][kt*32+k32]  with W = [WA | WB] along k.
__global__ void pack_w(const float* __restrict__ WA, int Ka,
                       const float* __restrict__ WB, int Kb,
                       short* __restrict__ dst, int N, long total) {
  long i = (long)blockIdx.x * blockDim.x + threadIdx.x;
  long stride = (long)gridDim.x * blockDim.x;
  for (; i < total; i += stride) {
    int c = (int)(i & 3);
    long r = i >> 2;
    int n = (int)(r % N);
    int kt = (int)(r / N);
    int k = kt * 32 + c * 8;
    const float* s = (k < Ka) ? (WA + (size_t)n * Ka + k)
                              : (WB + (size_t)n * Kb + (k - Ka));
    s8v o;
    #pragma unroll
    for (int j = 0; j < 8; ++j) o[j] = f2b(s[j]);
    *(s8v*)(dst + r * 32 + c * 8) = o;
  }
}

__global__ __launch_bounds__(64) void emb_gather(const int* __restrict__ tgt,
                                                 const float* __restrict__ emb,
                                                 short* __restrict__ dst) {
  int tb = blockIdx.x;                // 0..6399 = t*64+b
  int idx = tgt[tb];
  const float* s = emb + (size_t)idx * 512 + threadIdx.x * 8;
  s8v o;
  #pragma unroll
  for (int j = 0; j < 8; ++j) o[j] = f2b(s[j]);
  *(s8v*)(dst + (size_t)tb * 512 + threadIdx.x * 8) = o;
}

// c-state tile layout: c[bid*256 + lr*16 + lc] -> block-exclusive 1KB tiles.
__global__ void init_state(const float* __restrict__ h0, const float* __restrict__ c0,
                           short* __restrict__ h0r, short* __restrict__ h1r,
                           float* __restrict__ c0buf, float* __restrict__ c1buf,
                           short* __restrict__ feedr) {
  int i = blockIdx.x * 256 + threadIdx.x;
  if (i < 65536) {
    h0r[i] = f2b(h0[i]);          // ring slot 0
    h1r[i] = f2b(h0[65536 + i]);
    int row = i >> 10, col = i & 1023;
    size_t coff = (size_t)((row >> 4) * 64 + (col >> 4)) * 256
                + (row & 15) * 16 + (col & 15);
    c0buf[coff] = c0[i];
    c1buf[coff] = c0[65536 + i];
    feedr[i] = 0;                 // bf16 zero, slot 0
  }
}

// -------- GEMM core: dual-chain interleaved k-loop (depth-2 latency) -------

template <int NG>
DI void kloop_il(const short* __restrict__ A, int ld, int nkt,
                 const short* __restrict__ Wp, size_t wkt,
                 f4v* accA, f4v* accB, int rA, int g) {
  if (nkt <= 0) return;
  const short* ap = A + (size_t)rA * ld + 4 * g;
  int kt = 0;
  for (; kt + 1 < nkt; kt += 2) {
    const short* a0 = ap + kt * 32;
    const short* a1 = ap + (kt + 1) * 32;
    const short* b0 = Wp + (size_t)kt * wkt;
    const short* b1 = Wp + (size_t)(kt + 1) * wkt;
    s4v a0lo = *(const s4v*)a0, a0hi = *(const s4v*)(a0 + 16);
    s4v a1lo = *(const s4v*)a1, a1hi = *(const s4v*)(a1 + 16);
    s4v b0lo[NG], b0hi[NG], b1lo[NG], b1hi[NG];
    #pragma unroll
    for (int u = 0; u < NG; ++u) {
      b0lo[u] = *(const s4v*)(b0 + (size_t)u * 32768);
      b0hi[u] = *(const s4v*)(b0 + (size_t)u * 32768 + 16);
      b1lo[u] = *(const s4v*)(b1 + (size_t)u * 32768);
      b1hi[u] = *(const s4v*)(b1 + (size_t)u * 32768 + 16);
    }
    s8v aa = cat8(a0lo, a0hi), ab = cat8(a1lo, a1hi);
    #pragma unroll
    for (int u = 0; u < NG; ++u) {
      accA[u] = mfma16(aa, cat8(b0lo[u], b0hi[u]), accA[u]);
      accB[u] = mfma16(ab, cat8(b1lo[u], b1hi[u]), accB[u]);
    }
  }
  if (kt < nkt) {                 // odd tail -> chain A
    const short* a0 = ap + kt * 32;
    const short* b0 = Wp + (size_t)kt * wkt;
    s8v aa = cat8(*(const s4v*)a0, *(const s4v*)(a0 + 16));
    #pragma unroll
    for (int u = 0; u < NG; ++u)
      accA[u] = mfma16(aa, cat8(*(const s4v*)(b0 + (size_t)u * 32768),
                                *(const s4v*)(b0 + (size_t)u * 32768 + 16)),
                       accA[u]);
  }
}

// Up to 3 K-segments; this wave covers global k-tiles [k0,k1).
template <int NG>
DI void seg_gemm(const short* __restrict__ A0, int ld0, int n0,
                 const short* __restrict__ A1, int ld1, int n1,
                 const short* __restrict__ A2, int ld2, int n2,
                 const short* __restrict__ wbase, size_t wkt,
                 int k0, int k1, f4v* accA, f4v* accB, int rA, int g) {
  int s = 0;
  {
    int a = k0 > s ? k0 : s, b = k1 < (s + n0) ? k1 : (s + n0);
    if (a < b) kloop_il<NG>(A0 + (size_t)(a - s) * 32, ld0, b - a,
                            wbase + (size_t)a * wkt, wkt, accA, accB, rA, g);
    s += n0;
  }
  {
    int a = k0 > s ? k0 : s, b = k1 < (s + n1) ? k1 : (s + n1);
    if (a < b) kloop_il<NG>(A1 + (size_t)(a - s) * 32, ld1, b - a,
                            wbase + (size_t)a * wkt, wkt, accA, accB, rA, g);
    s += n1;
  }
  if (n2 > 0) {
    int a = k0 > s ? k0 : s, b = k1 < (s + n2) ? k1 : (s + n2);
    if (a < b) kloop_il<NG>(A2 + (size_t)(a - s) * 32, ld2, b - a,
                            wbase + (size_t)a * wkt, wkt, accA, accB, rA, g);
  }
}

// Sum the 4 waves' partial accumulators via LDS. Wave 0 holds the total.
template <int NG>
DI void wave_reduce(f4v* acc, float* smem, int w, int l) {
  #pragma unroll
  for (int t4 = 0; t4 < NG; ++t4)
    *(f4v*)&smem[(w * 64 + l) * 20 + t4 * 4] = acc[t4];
  __syncthreads();
  if (w == 0) {
    #pragma unroll
    for (int t4 = 0; t4 < NG; ++t4) {
      f4v s0 = *(f4v*)&smem[l * 20 + t4 * 4];
      #pragma unroll
      for (int ww = 1; ww < 4; ++ww) {
        f4v v = *(f4v*)&smem[(ww * 64 + l) * 20 + t4 * 4];
        #pragma unroll
        for (int j = 0; j < 4; ++j) s0[j] += v[j];
      }
      acc[t4] = s0;
    }
  }
}

// ---- dependency-exact group sync: store-slot counters ---------------------
// Slots 16-int (64B) strided, monotonic (posted value = t+1).
//   s_p1 @ 0, s_p2 @ 4096, s_p3 @ 8192, s_p6 @ 12288   [slot rt*64+cs]
//   s_p4 @ 16384, s_mg @ 20480                          [slot b*4+chunk]

DI void post(int* slot, int val) {   // call AFTER a draining __syncthreads
  if (threadIdx.x == 0) st32c(slot, val);
}
DI void wait64(const int* slots, int want) {   // 64 producer slots
  for (;;) {
    int ok = 1;
    if (threadIdx.x < 64) ok = (ld32c(slots + threadIdx.x * 16) >= want);
    if (__syncthreads_and(ok)) break;
    __builtin_amdgcn_s_sleep(4);
  }
}
DI void wait4(const int* slots, int want) {    // 4 sibling slots
  for (;;) {
    int ok = 1;
    if (threadIdx.x < 4) ok = (ld32c(slots + threadIdx.x * 16) >= want);
    if (__syncthreads_and(ok)) break;
    __builtin_amdgcn_s_sleep(2);
  }
}

// ---------------- the persistent decoder kernel ----------------------------

__global__ __launch_bounds__(256, 1) void decoder_k(
    const short* __restrict__ W0p, const short* __restrict__ W1p,
    const short* __restrict__ Wop, const short* __restrict__ Wap,
    const short* __restrict__ emba,
    const float* __restrict__ bi0, const float* __restrict__ bh0,
    const float* __restrict__ bi1, const float* __restrict__ bh1,
    short* h0r, short* h1r, short* feedr, short* ctxr, short* qb,
    float* c0b, float* c1b, float* alg, float* part, float* csum,
    const short* __restrict__ Mb, const float* __restrict__ memf,
    float* out, int useMb, int* bar) {
  __shared__ float smem[5248];
  __shared__ __align__(16) short htile[256];
  __shared__ __align__(16) float ftile[256];
  const int bid = blockIdx.x, tid = threadIdx.x;
  const int w = tid >> 6, l = tid & 63, r15 = l & 15, g = l >> 4;
  const int cs = bid & 63, rt = bid >> 6;
  const int b = bid & 63, chunk = bid >> 6;        // attention role
  int* s_p1 = bar;
  int* s_p2 = bar + 4096;
  int* s_p3 = bar + 8192;
  int* s_p6 = bar + 12288;
  int* s_p4 = bar + 16384;
  int* s_mg = bar + 20480;
  f4v z = {0.f, 0.f, 0.f, 0.f};

  for (int t = 0; t < 100; ++t) {
    const size_t scur = (size_t)t * 65536, snxt = (size_t)(t + 1) * 65536;

    // ---- P1: LSTM0 gates (N=4096, K=2560: emb512|feed1024|h0 1024) ----
    {
      wait64(s_p6 + rt * 1024, t);          // feed[t] rows rt*16 ready
      f4v accA[4] = {z, z, z, z}, accB[4] = {z, z, z, z};
      const short* wbase = W0p + (size_t)(cs * 16 + r15) * 32 + 4 * g;
      seg_gemm<4>(emba + (size_t)t * 64 * 512, 512, 16,
                  feedr + scur, 1024, 32, h0r + scur, 1024, 32,
                  wbase, (size_t)4096 * 32, w * 20, w * 20 + 20,
                  accA, accB, rt * 16 + r15, g);
      #pragma unroll
      for (int u = 0; u < 4; ++u)
        #pragma unroll
        for (int j = 0; j < 4; ++j) accA[u][j] += accB[u][j];
      wave_reduce<4>(accA, smem, w, l);
      if (w == 0) {
        int h = cs * 16 + r15;
        float bs0 = bi0[h] + bh0[h];
        float bs1 = bi0[1024 + h] + bh0[1024 + h];
        float bs2 = bi0[2048 + h] + bh0[2048 + h];
        float bs3 = bi0[3072 + h] + bh0[3072 + h];
        #pragma unroll
        for (int q = 0; q < 4; ++q) {
          size_t coff = (size_t)bid * 256 + (g * 4 + q) * 16 + r15;
          float iv = accA[0][q] + bs0, fv = accA[1][q] + bs1;
          float gv = accA[2][q] + bs2, ov = accA[3][q] + bs3;
          float cn = sigm(fv) * c0b[coff] + sigm(iv) * tanhf(gv);
          float hn = sigm(ov) * tanhf(cn);
          c0b[coff] = cn;                   // block-EXCLUSIVE tile: safe
          htile[(g * 4 + q) * 16 + r15] = f2b(hn);
        }
      }
      __syncthreads();
      if (tid < 32) {                       // 32 x 16B write-through stores
        int row = tid >> 1, c8 = (tid & 1) * 8;
        st128c(h0r + snxt + (size_t)(rt * 16 + row) * 1024 + cs * 16 + c8,
               *(const s8v*)&htile[row * 16 + c8]);
      }
      __syncthreads();                      // drain epilogue stores
      post(s_p1 + (rt * 64 + cs) * 16, t + 1);
    }

    // ---- P2: LSTM1 gates (K=2048: h0[t+1] | h1[t]) ----
    {
      wait64(s_p1 + rt * 1024, t + 1);
      f4v accA[4] = {z, z, z, z}, accB[4] = {z, z, z, z};
      const short* wbase = W1p + (size_t)(cs * 16 + r15) * 32 + 4 * g;
      seg_gemm<4>(h0r + snxt, 1024, 32, h1r + scur, 1024, 32,
                  (const short*)nullptr, 0, 0,
                  wbase, (size_t)4096 * 32, w * 16, w * 16 + 16,
                  accA, accB, rt * 16 + r15, g);
      #pragma unroll
      for (int u = 0; u < 4; ++u)
        #pragma unroll
        for (int j = 0; j < 4; ++j) accA[u][j] += accB[u][j];
      wave_reduce<4>(accA, smem, w, l);
      if (w == 0) {
        int h = cs * 16 + r15;
        float bs0 = bi1[h] + bh1[h];
        float bs1 = bi1[1024 + h] + bh1[1024 + h];
        float bs2 = bi1[2048 + h] + bh1[2048 + h];
        float bs3 = bi1[3072 + h] + bh1[3072 + h];
        #pragma unroll
        for (int q = 0; q < 4; ++q) {
          size_t coff = (size_t)bid * 256 + (g * 4 + q) * 16 + r15;
          float iv = accA[0][q] + bs0, fv = accA[1][q] + bs1;
          float gv = accA[2][q] + bs2, ov = accA[3][q] + bs3;
          float cn = sigm(fv) * c1b[coff] + sigm(iv) * tanhf(gv);
          float hn = sigm(ov) * tanhf(cn);
          c1b[coff] = cn;
          htile[(g * 4 + q) * 16 + r15] = f2b(hn);
        }
      }
      __syncthreads();
      if (tid < 32) {
        int row = tid >> 1, c8 = (tid & 1) * 8;
        st128c(h1r + snxt + (size_t)(rt * 16 + row) * 1024 + cs * 16 + c8,
               *(const s8v*)&htile[row * 16 + c8]);
      }
      __syncthreads();
      post(s_p2 + (rt * 64 + cs) * 16, t + 1);
    }

    // ---- P3: qproj (N=1024, K=1024) ----
    {
      wait64(s_p2 + rt * 1024, t + 1);
      f4v accA[1] = {z}, accB[1] = {z};
      const short* wbase = Wap + (size_t)(cs * 16 + r15) * 32 + 4 * g;
      seg_gemm<1>(h1r + snxt, 1024, 32, (const short*)nullptr, 0, 0,
                  (const short*)nullptr, 0, 0,
                  wbase, (size_t)1024 * 32, w * 8, w * 8 + 8,
                  accA, accB, rt * 16 + r15, g);
      #pragma unroll
      for (int j = 0; j < 4; ++j) accA[0][j] += accB[0][j];
      wave_reduce<1>(accA, smem, w, l);
      if (w == 0) {
        #pragma unroll
        for (int q = 0; q < 4; ++q)
          htile[(g * 4 + q) * 16 + r15] = f2b(accA[0][q]);
      }
      __syncthreads();
      if (tid < 32) {
        int row = tid >> 1, c8 = (tid & 1) * 8;
        st128c(qb + (size_t)(rt * 16 + row) * 1024 + cs * 16 + c8,
               *(const s8v*)&htile[row * 16 + c8]);
      }
      __syncthreads();
      post(s_p3 + (rt * 64 + cs) * 16, t + 1);
    }

    // ---- P4: attention partial + fused merge (group-local sync) ----
    {
      wait64(s_p3 + (b >> 4) * 1024, t + 1); // q row b ready (group b>>4)
      wait4(s_mg + b * 64, t);               // WAR: prev merge reads done
      int s0 = chunk * 151;
      int send = 602 < s0 + 151 ? 602 : s0 + 151;
      const short* qp = qb + (size_t)b * 1024 + l * 16;
      float qf[16];
      #pragma unroll
      for (int c4 = 0; c4 < 4; ++c4) {
        U64S x; x.u = ld64c(qp + c4 * 4);
        #pragma unroll
        for (int j = 0; j < 4; ++j) qf[c4 * 4 + j] = b2f(x.s[j]);
      }
      float o[16];
      #pragma unroll
      for (int j = 0; j < 16; ++j) o[j] = 0.f;
      float ls8 = 0.f;
      for (int s = s0 + w; s < send; s += 16) {
        int sr[4] = {s, s + 4, s + 8, s + 12};
        bool has[4];
        #pragma unroll
        for (int r = 0; r < 4; ++r) has[r] = sr[r] < send;
        float mv[4][16];
        if (useMb) {
          #pragma unroll
          for (int r = 0; r < 4; ++r) {
            int sx = has[r] ? sr[r] : s;
            const short* mp = Mb + ((size_t)sx * 64 + b) * 1024 + l * 16;
            s8v a0 = *(const s8v*)mp, a1 = *(const s8v*)(mp + 8);
            #pragma unroll
            for (int j = 0; j < 8; ++j) {
              mv[r][j] = b2f(a0[j]); mv[r][8 + j] = b2f(a1[j]);
            }
          }
        } else {
          #pragma unroll
          for (int r = 0; r < 4; ++r) {
            int sx = has[r] ? sr[r] : s;
            const float* mp = memf + ((size_t)sx * 64 + b) * 1024 + l * 16;
            f4v a0 = *(const f4v*)mp, a1 = *(const f4v*)(mp + 4);
            f4v a2 = *(const f4v*)(mp + 8), a3 = *(const f4v*)(mp + 12);
            #pragma unroll
            for (int j = 0; j < 4; ++j) {
              mv[r][j] = a0[j]; mv[r][4 + j] = a1[j];
              mv[r][8 + j] = a2[j]; mv[r][12 + j] = a3[j];
            }
          }
        }
        float d[4] = {0.f, 0.f, 0.f, 0.f};
        #pragma unroll
        for (int j = 0; j < 16; ++j) {
          #pragma unroll
          for (int r = 0; r < 4; ++r) d[r] += qf[j] * mv[r][j];
        }
        #pragma unroll
        for (int off = 32; off; off >>= 1) {
          #pragma unroll
          for (int r = 0; r < 4; ++r) d[r] += __shfl_down(d[r], off);
        }
        float p[4];
        #pragma unroll
        for (int r = 0; r < 4; ++r) {
          d[r] = __shfl(d[r], 0);
          p[r] = has[r] ? __expf(fminf(d[r], 80.f) - 8.f) : 0.f;
          ls8 += p[r];
        }
        if (l == 0) {
          #pragma unroll
          for (int r = 0; r < 4; ++r)
            if (has[r]) stfc(alg + b * 602 + sr[r], p[r]);
        }
        #pragma unroll
        for (int j = 0; j < 16; ++j)
          o[j] += p[0] * mv[0][j] + p[1] * mv[1][j]
                + p[2] * mv[2][j] + p[3] * mv[3][j];
      }
      float* pp = part + (size_t)(b * 16 + chunk * 4 + w) * 1024;
      #pragma unroll
      for (int j4 = 0; j4 < 8; ++j4) {
        U64F x; x.f[0] = o[j4 * 2]; x.f[1] = o[j4 * 2 + 1];
        st64c(pp + l * 16 + j4 * 2, x.u);
      }
      if (l == 0) smem[5120 + w] = ls8;
      __syncthreads();                    // drains part stores + ls8 to LDS
      if (tid == 0)
        stfc(csum + b * 4 + chunk,
             smem[5120] + smem[5121] + smem[5122] + smem[5123]);
      __syncthreads();                    // drains tid0's csum store
      post(s_p4 + (b * 4 + chunk) * 16, t + 1);
      wait4(s_p4 + b * 64, t + 1);        // siblings' partials ready
      // fused merge: fixed-shift softmax is exact (shift-invariant)
      {
        const float* cs4 = csum + b * 4;
        float L8 = ldfc(cs4) + ldfc(cs4 + 1) + ldfc(cs4 + 2) + ldfc(cs4 + 3);
        float invL = 1.f / L8;
        if (tid < 128) {                  // this block's 256 ctx cols
          int h = chunk * 256 + tid * 2;
          float a0 = 0.f, a1 = 0.f;
          #pragma unroll
          for (int p = 0; p < 16; ++p) {
            U64F x; x.u = ld64c(part + (size_t)(b * 16 + p) * 1024 + h);
            a0 += x.f[0]; a1 += x.f[1];
          }
          short* cp = ctxr + snxt + (size_t)b * 1024 + h;
          st16c(cp, f2b(a0 * invL));
          st16c(cp + 1, f2b(a1 * invL));
        }
        float* attns = out + 6553600 + (size_t)t * 64 * 602;
        for (int i = s0 + tid; i < send; i += 256)
          stfc(attns + b * 602 + i, ldfc(alg + b * 602 + i) * invL);
      }
      __syncthreads();                    // drain ctx/attns + part reads done
      post(s_mg + (b * 4 + chunk) * 16, t + 1);
    }

    // ---- P6: out projection + tanh (N=1024, K=2048: ctx[t+1]|h1[t+1]) ----
    {
      wait64(s_mg + rt * 1024, t + 1);    // ctx rows rt*16 ready
      f4v accA[1] = {z}, accB[1] = {z};
      const short* wbase = Wop + (size_t)(cs * 16 + r15) * 32 + 4 * g;
      seg_gemm<1>(ctxr + snxt, 1024, 32, h1r + snxt, 1024, 32,
                  (const short*)nullptr, 0, 0,
                  wbase, (size_t)1024 * 32, w * 16, w * 16 + 16,
                  accA, accB, rt * 16 + r15, g);
      #pragma unroll
      for (int j = 0; j < 4; ++j) accA[0][j] += accB[0][j];
      wave_reduce<1>(accA, smem, w, l);
      if (w == 0) {
        #pragma unroll
        for (int q = 0; q < 4; ++q) {
          float v = tanhf(accA[0][q]);
          ftile[(g * 4 + q) * 16 + r15] = v;
          htile[(g * 4 + q) * 16 + r15] = f2b(v);
        }
      }
      __syncthreads();
      if (tid < 32) {
        int row = tid >> 1, c8 = (tid & 1) * 8;
        st128c(feedr + snxt + (size_t)(rt * 16 + row) * 1024 + cs * 16 + c8,
               *(const s8v*)&htile[row * 16 + c8]);
      }
      if (tid >= 64 && tid < 128) {       // out: 64 x 16B f32 stores
        int x = tid - 64;
        int row = x >> 2, c4 = (x & 3) * 4;
        st128cf(out + (size_t)t * 65536 +
                (size_t)(rt * 16 + row) * 1024 + cs * 16 + c4,
                *(const f4v*)&ftile[row * 16 + c4]);
      }
      __syncthreads();
      post(s_p6 + (rt * 64 + cs) * 16, t + 1);
    }
  }
}

// ---------------- launcher -------------------------------------------------

extern "C" void kernel_launch(void* const* d_in, const int* in_sizes, int n_in,
                              void* d_out, int out_size, void* d_ws, size_t ws_size,
                              hipStream_t stream) {
  const int*   tgt  = (const int*)  d_in[0];
  const float* mem  = (const float*)d_in[1];
  const float* h0   = (const float*)d_in[2];
  const float* c0   = (const float*)d_in[3];
  const float* embw = (const float*)d_in[4];
  const float* Wi0  = (const float*)d_in[5];
  const float* Wh0  = (const float*)d_in[6];
  const float* bi0  = (const float*)d_in[7];
  const float* bh0  = (const float*)d_in[8];
  const float* Wi1  = (const float*)d_in[9];
  const float* Wh1  = (const float*)d_in[10];
  const float* bi1  = (const float*)d_in[11];
  const float* bh1  = (const float*)d_in[12];
  const float* Wat  = (const float*)d_in[13];
  const float* Wou  = (const float*)d_in[14];
  float* out = (float*)d_out;

  char* base = (char*)d_ws;
  size_t off = 0;
  auto alloc = [&](size_t bytes) -> void* {
    void* p = base + off;
    off += (bytes + 255) & ~(size_t)255;
    return p;
  };
  const size_t RING = (size_t)101 * 65536;   // 101 slots x 64x1024 bf16
  int* bar = (int*)alloc(131072);  // 6 x 256 sync slots (64B strided)
  short* qb   = (short*)alloc(65536 * 2);
  float* csum = (float*)alloc(64 * 4 * 4);
  float* c0b  = (float*)alloc(65536 * 4);
  float* c1b  = (float*)alloc(65536 * 4);
  float* alg  = (float*)alloc((size_t)64 * 602 * 4);
  float* part = (float*)alloc((size_t)64 * 16 * 1024 * 4);
  short* emba = (short*)alloc((size_t)100 * 64 * 512 * 2);
  short* Wap  = (short*)alloc((size_t)32 * 1024 * 32 * 2);
  short* Wop  = (short*)alloc((size_t)64 * 1024 * 32 * 2);
  short* W1p  = (short*)alloc((size_t)64 * 4096 * 32 * 2);
  short* W0p  = (short*)alloc((size_t)80 * 4096 * 32 * 2);
  short* h0r  = (short*)alloc(RING * 2);
  short* h1r  = (short*)alloc(RING * 2);
  short* feedr= (short*)alloc(RING * 2);
  short* ctxr = (short*)alloc(RING * 2);
  const size_t MBE = (size_t)602 * 64 * 1024;
  bool useMb = (off + MBE * 2 + 256) <= ws_size;
  short* Mb = useMb ? (short*)alloc(MBE * 2) : nullptr;

  hipMemsetAsync(bar, 0, 131072, stream);
  hipLaunchKernelGGL(emb_gather, dim3(6400), dim3(64), 0, stream, tgt, embw, emba);
  hipLaunchKernelGGL(pack_w, dim3(2048), dim3(256), 0, stream, Wi0, 1536, Wh0, 1024,
                     W0p, 4096, (long)80 * 4096 * 4);
  hipLaunchKernelGGL(pack_w, dim3(2048), dim3(256), 0, stream, Wi1, 1024, Wh1, 1024,
                     W1p, 4096, (long)64 * 4096 * 4);
  hipLaunchKernelGGL(pack_w, dim3(1024), dim3(256), 0, stream, Wou, 2048, Wou, 2048,
                     Wop, 1024, (long)64 * 1024 * 4);
  hipLaunchKernelGGL(pack_w, dim3(512), dim3(256), 0, stream, Wat, 1024, Wat, 1024,
                     Wap, 1024, (long)32 * 1024 * 4);
  hipLaunchKernelGGL(init_state, dim3(256), dim3(256), 0, stream, h0, c0,
                     h0r, h1r, c0b, c1b, feedr);
  if (useMb)
    hipLaunchKernelGGL(cvt_bf16, dim3(2048), dim3(256), 0, stream, mem, Mb,
                       (long)(MBE / 8));

  hipLaunchKernelGGL(decoder_k, dim3(256), dim3(256), 0, stream,
                     W0p, W1p, Wop, Wap, emba,
                     bi0, bh0, bi1, bh1,
                     h0r, h1r, feedr, ctxr, qb,
                     c0b, c1b, alg, part, csum,
                     Mb, mem, out, (int)useMb,
                     bar);
}